// Round 6
// baseline (215.721 us; speedup 1.0000x reference)
//
#include <hip/hip_runtime.h>
#include <hip/hip_bf16.h>
#include <stdint.h>
#include <stddef.h>

typedef __bf16 bf16_t;
typedef __attribute__((ext_vector_type(8))) __bf16 bf16x8;   // 4 VGPRs, MFMA A/B operand
typedef __attribute__((ext_vector_type(4))) float f32x4;     // MFMA C/D (16x16)
typedef __attribute__((ext_vector_type(16))) float f32x16;   // MFMA C/D (32x32)
typedef __attribute__((ext_vector_type(4))) unsigned u32x4;

#define MFMA_BF16(a, b, c) __builtin_amdgcn_mfma_f32_16x16x32_bf16((a), (b), (c), 0, 0, 0)
#define MFMA32(a, b, c)    __builtin_amdgcn_mfma_f32_32x32x16_bf16((a), (b), (c), 0, 0, 0)

// pack two f32 -> one u32 of 2 bf16 (lo = x, hi = y)
static __device__ __forceinline__ unsigned pk2(float x, float y) {
  const unsigned short lo = __builtin_bit_cast(unsigned short, (__bf16)x);
  const unsigned short hi = __builtin_bit_cast(unsigned short, (__bf16)y);
  return ((unsigned)hi << 16) | lo;
}

// ---------------- dtype detector (inputs are f32 in practice; keep robust) ------
__global__ void detect_dtype(const unsigned short* __restrict__ x, int* __restrict__ flag) {
  __shared__ int cnt;
  if (threadIdx.x == 0) cnt = 0;
  __syncthreads();
  int local = 0;
  for (int i = threadIdx.x; i < 16384; i += 256) {
    const int e = (x[i] >> 7) & 0xFF;
    if (e >= 0x8D) local++;
  }
  atomicAdd(&cnt, local);
  __syncthreads();
  if (threadIdx.x == 0) *flag = (cnt > 16) ? 1 : 0;
}

// ---------------- x -> bf16 prepass (into d_out lower half; dead until proj) ----
__global__ void cvt_x(const float* __restrict__ in, bf16_t* __restrict__ out,
                      const int* __restrict__ flagp) {
  if (!*flagp) return;  // already bf16; GEMM reads x directly
  const size_t i = ((size_t)blockIdx.x * 256 + threadIdx.x) * 8;
  const float4 a = *(const float4*)(in + i), b = *(const float4*)(in + i + 4);
  bf16x8 r;
  r[0] = (__bf16)a.x; r[1] = (__bf16)a.y; r[2] = (__bf16)a.z; r[3] = (__bf16)a.w;
  r[4] = (__bf16)b.x; r[5] = (__bf16)b.y; r[6] = (__bf16)b.z; r[7] = (__bf16)b.w;
  *(bf16x8*)(out + i) = r;
}

// ---------------- transpose (any input dtype -> bf16): out[c][r] = in[r][c] ------
__global__ void transpose_any(const void* __restrict__ in, bf16_t* __restrict__ out,
                              int R, int C, const int* __restrict__ flagp) {
  const int isF32 = *flagp;
  __shared__ bf16_t tile[32][33];
  const int tx = threadIdx.x, ty = threadIdx.y;
  const int r0 = blockIdx.y * 32, c0 = blockIdx.x * 32;
#pragma unroll
  for (int i = 0; i < 4; ++i) {
    const size_t idx = (size_t)(r0 + ty + i * 8) * C + (c0 + tx);
    tile[ty + i * 8][tx] = isF32 ? (bf16_t)((const float*)in)[idx]
                                 : ((const bf16_t*)in)[idx];
  }
  __syncthreads();
#pragma unroll
  for (int i = 0; i < 4; ++i)
    out[(size_t)(c0 + ty + i * 8) * R + (r0 + tx)] = tile[tx][ty + i * 8];
}

// ---------------- GEMM: C = A * Bt^T + bias --------------------------------------
// (R4 version — the known-good 194.6us config; R5's depth-2/setprio edits reverted)
// 128x128 tile, BK=64, register-prefetch staging, padded LDS stride 72.
// MODE 1: scatter Q*0.125*log2e -> Qs, K -> Kb; V-blocks (n0>=2048) transpose
//         tile through LDS -> coalesced 16B stores to Vt (d_out hi).
// MODE 2: A = head-major attn out in Qs (h = k0>>6 exact at BK=64); plain C store.
#define GP 72
template <int MODE>
__global__ __launch_bounds__(256) void gemm_bt(const void* A0,
                        const bf16_t* __restrict__ xb,
                        const bf16_t* __restrict__ Bt,
                        const void* __restrict__ bias,
                        void* C,
                        bf16_t* __restrict__ Qs,
                        bf16_t* __restrict__ Kb,
                        bf16_t* __restrict__ dout_bf,
                        int M, int N, int K,
                        const int* __restrict__ flagp) {
  const int isF32 = *flagp;
  const bf16_t* A = (MODE == 1 && isF32) ? xb : (const bf16_t*)A0;
  bf16_t* Vt = dout_bf + (isF32 ? (size_t)4194304 : 0);  // d_out hi half if f32 out

  __shared__ __align__(16) unsigned char pool[128 * GP * 2 * 2];
  bf16_t* As = (bf16_t*)pool;
  bf16_t* Bs = (bf16_t*)pool + 128 * GP;

  const int tid = threadIdx.x;
  const int w = tid >> 6, lane = tid & 63;
  const int quad = lane >> 4, l16 = lane & 15;
  const int wm = w >> 1, wn = w & 1;
  const int m0 = blockIdx.y * 128, n0 = blockIdx.x * 128;

  auto loadA = [&](int k0, int it) -> bf16x8 {
    const int g = it * 256 + tid;
    const int row = g >> 3, col = (g & 7) * 8;
    const int m = m0 + row;
    if (MODE == 2) {
      const size_t aoff =
          ((size_t)((m >> 11) * 16 + (k0 >> 6)) * 2048 + (m & 2047)) * 64 + col;
      return *(const bf16x8*)(A + aoff);
    }
    return *(const bf16x8*)(A + (size_t)m * K + (k0 + col));
  };
  auto loadB = [&](int k0, int it) -> bf16x8 {
    const int g = it * 256 + tid;
    const int row = g >> 3, col = (g & 7) * 8;
    return *(const bf16x8*)(Bt + (size_t)(n0 + row) * K + (k0 + col));
  };

  f32x4 acc[4][4];
#pragma unroll
  for (int i = 0; i < 4; ++i)
#pragma unroll
    for (int j = 0; j < 4; ++j) acc[i][j] = f32x4{0.f, 0.f, 0.f, 0.f};

  bf16x8 va[4], vb[4];
#pragma unroll
  for (int it = 0; it < 4; ++it) { va[it] = loadA(0, it); vb[it] = loadB(0, it); }

  for (int k0 = 0; k0 < K; k0 += 64) {
    __syncthreads();
#pragma unroll
    for (int it = 0; it < 4; ++it) {
      const int g = it * 256 + tid;
      const int row = g >> 3, col = (g & 7) * 8;
      *(bf16x8*)&As[row * GP + col] = va[it];
      *(bf16x8*)&Bs[row * GP + col] = vb[it];
    }
    __syncthreads();

    if (k0 + 64 < K) {
#pragma unroll
      for (int it = 0; it < 4; ++it) { va[it] = loadA(k0 + 64, it); vb[it] = loadB(k0 + 64, it); }
    }

#pragma unroll
    for (int kc = 0; kc < 2; ++kc) {
      bf16x8 af[4], bfr[4];
#pragma unroll
      for (int i = 0; i < 4; ++i)
        af[i] = *(const bf16x8*)&As[(wm * 64 + i * 16 + l16) * GP + kc * 32 + quad * 8];
#pragma unroll
      for (int j = 0; j < 4; ++j)
        bfr[j] = *(const bf16x8*)&Bs[(wn * 64 + j * 16 + l16) * GP + kc * 32 + quad * 8];
#pragma unroll
      for (int i = 0; i < 4; ++i)
#pragma unroll
        for (int j = 0; j < 4; ++j) acc[i][j] = MFMA_BF16(af[i], bfr[j], acc[i][j]);
    }
  }

  // ---------------- epilogue — C/D layout: row = quad*4 + r, col = l16 ----------
  if (MODE == 1 && n0 >= 2048) {
    bf16_t* tp = (bf16_t*)pool;  // [n_local][m_local], stride 136
    __syncthreads();
#pragma unroll
    for (int j = 0; j < 4; ++j) {
      const int n_l = wn * 64 + j * 16 + l16;
      const int n = n0 + n_l;
      const float bj = isF32 ? ((const float*)bias)[n] : (float)((const bf16_t*)bias)[n];
#pragma unroll
      for (int i = 0; i < 4; ++i) {
#pragma unroll
        for (int r = 0; r < 4; ++r) {
          const int m_l = wm * 64 + i * 16 + quad * 4 + r;
          tp[n_l * 136 + m_l] = (bf16_t)(acc[i][j][r] + bj);
        }
      }
    }
    __syncthreads();
    const int b = m0 >> 11, s0 = m0 & 2047;
#pragma unroll
    for (int seg = 0; seg < 8; ++seg) {
      const int idx = seg * 256 + tid;
      const int n_l = idx >> 4, ms = (idx & 15) * 8;
      const bf16x8 v8 = *(const bf16x8*)&tp[n_l * 136 + ms];
      const int e = (n0 + n_l) & 1023, h = e >> 6, d = e & 63;
      *(bf16x8*)(Vt + ((size_t)(b * 16 + h) * 64 + d) * 2048 + s0 + ms) = v8;
    }
    return;
  }

#pragma unroll
  for (int j = 0; j < 4; ++j) {
    const int n = n0 + wn * 64 + j * 16 + l16;
    const float bj = isF32 ? ((const float*)bias)[n] : (float)((const bf16_t*)bias)[n];
#pragma unroll
    for (int i = 0; i < 4; ++i) {
      const int mbase = m0 + wm * 64 + i * 16 + quad * 4;
#pragma unroll
      for (int r = 0; r < 4; ++r) {
        const int m = mbase + r;
        const float v = acc[i][j][r] + bj;
        if (MODE == 2) {
          if (isF32) ((float*)C)[(size_t)m * N + n] = v;
          else       ((bf16_t*)C)[(size_t)m * N + n] = (bf16_t)v;
        } else {
          const int e = n & 1023;
          const int h = e >> 6, d = e & 63;
          const int bb = m >> 11, s = m & 2047;
          const size_t bh = (size_t)(bb * 16 + h);
          if ((n >> 10) == 0) Qs[(bh * 2048 + s) * 64 + d] = (bf16_t)(v * 0.18033688011f);
          else                Kb[(bh * 2048 + s) * 64 + d] = (bf16_t)v;
        }
      }
    }
  }
}

// ---------------- causal flash attention -----------------------------------------
// v6: 32x32x16 MFMA restructure — the LDS-pipe fix.
// Per wave-tile LDS instrs drop 1.5/q -> 0.75/q: 32x32 operands amortize each
// b128 read over 2x FLOPs, and P NEVER touches LDS (in-register cvt+pack +
// v_permlane32_swap half-exchange builds the PV A-fragment; VALU pipe).
// Block = 2 waves (128 thr) over a 64-q tile, wave = 32 q. 1024 blocks, v4's
// balanced decode (any stride-256 class = 66 tile-iters). LDS 18.4KB, 4 blk/CU.
// Layouts (guide-verified m74/m101): 32x32 C/D col=lane&31, row=(reg&3)+8*(reg>>2)
// +4*(lane>>5); A row=lane&31, B col=lane&31, k=(lane>>5)*8+e (A/B k-maps cancel).
// QK: S[key][q] = K·Q^T -> lane owns score column q=lane&31 (lsum lane-local,
// one shfl_xor(32) at end). PV: O[q][d] = P·V, A=P assembled in-register.
#define AP 72
__global__ __launch_bounds__(128, 2) void attn_kernel(bf16_t* QO,
                                                      const bf16_t* __restrict__ Kb,
                                                      const bf16_t* __restrict__ dout_bf,
                                                      const int* __restrict__ flagp) {
  const int isF32 = *flagp;
  const bf16_t* Vt = dout_bf + (isF32 ? (size_t)4194304 : 0);

  __shared__ __align__(16) bf16_t Ks[64 * AP];  // [key][d]
  __shared__ __align__(16) bf16_t Vs[64 * AP];  // [d][key]

  const int bid = blockIdx.x;
  const int g = bid >> 5, bh = bid & 31;
  const int qt = (g < 16) ? (31 - g) : (g - 16);  // balanced + longest-first

  const int tid = threadIdx.x, w = tid >> 6, lane = tid & 63;
  const int c = lane & 31, hi = lane >> 5;        // col (q or d), k-half

  bf16_t* Q = QO + (size_t)bh * 2048 * 64;
  const bf16_t* K = Kb + (size_t)bh * 2048 * 64;
  const bf16_t* V = Vt + (size_t)bh * 64 * 2048;

  const int qrow = qt * 64 + w * 32;              // this wave's 32 q-rows
  const int nkt = qt + 1;                         // causal 64-key tiles

  // Q B-fragments: col=q=c, k=d = ks*16 + hi*8 + 0..7
  bf16x8 qf[4];
#pragma unroll
  for (int ks = 0; ks < 4; ++ks)
    qf[ks] = *(const bf16x8*)(Q + (size_t)(qrow + c) * 64 + ks * 16 + hi * 8);

  f32x16 oacc0 = {0,0,0,0,0,0,0,0,0,0,0,0,0,0,0,0};
  f32x16 oacc1 = {0,0,0,0,0,0,0,0,0,0,0,0,0,0,0,0};
  float lsum = 0.f;

  // staging: 128 threads x 4 x 16B per buffer = full 64x64 bf16 tile
  const int srow = tid >> 3;          // 0..15
  const int scol = (tid & 7) * 8;     // 0..56

  auto loadK = [&](int kt, int it) -> bf16x8 {
    return *(const bf16x8*)(K + (size_t)(kt * 64 + it * 16 + srow) * 64 + scol);
  };
  auto loadV = [&](int kt, int it) -> bf16x8 {
    return *(const bf16x8*)(V + (size_t)(it * 16 + srow) * 2048 + kt * 64 + scol);
  };

  bf16x8 kv[4], vv[4];
#pragma unroll
  for (int it = 0; it < 4; ++it) { kv[it] = loadK(0, it); vv[it] = loadV(0, it); }

  for (int kt = 0; kt < nkt; ++kt) {
    __syncthreads();  // prev iter's Ks/Vs fragment reads done
#pragma unroll
    for (int it = 0; it < 4; ++it) {
      *(bf16x8*)&Ks[(it * 16 + srow) * AP + scol] = kv[it];  // Ks[key][d]
      *(bf16x8*)&Vs[(it * 16 + srow) * AP + scol] = vv[it];  // Vs[d][key]
    }
    __syncthreads();

    // prefetch next tile; stays in flight through QK/softmax/PV
    if (kt + 1 < nkt) {
#pragma unroll
      for (int it = 0; it < 4; ++it) { kv[it] = loadK(kt + 1, it); vv[it] = loadV(kt + 1, it); }
    }

    // S = K Q^T: keyblk 0 -> s0 (keys 0-31), keyblk 1 -> s1 (keys 32-63)
    f32x16 s0 = {0,0,0,0,0,0,0,0,0,0,0,0,0,0,0,0};
    f32x16 s1 = {0,0,0,0,0,0,0,0,0,0,0,0,0,0,0,0};
#pragma unroll
    for (int ks = 0; ks < 4; ++ks) {
      const bf16x8 kf0 = *(const bf16x8*)&Ks[(c)      * AP + ks * 16 + hi * 8];
      const bf16x8 kf1 = *(const bf16x8*)&Ks[(32 + c) * AP + ks * 16 + hi * 8];
      s0 = MFMA32(kf0, qf[ks], s0);
      s1 = MFMA32(kf1, qf[ks], s1);
    }

    if (kt * 64 + 63 > qrow) {  // diagonal tile only
      const int qg = qrow + c;
#pragma unroll
      for (int j = 0; j < 16; ++j) {
        const int key = kt * 64 + (j & 3) + 8 * (j >> 2) + 4 * hi;
        if (key > qg)      s0[j] = -1e30f;
        if (key + 32 > qg) s1[j] = -1e30f;
      }
    }

    // no-max softmax (exp2 domain) + in-register bf16 pack.
    // w0[t]/w1[t] hold key-pair (base = kb*32 + 8*(t>>1) + 4*hi + 2*(t&1)).
    unsigned w0[8], w1[8];
#pragma unroll
    for (int t = 0; t < 8; ++t) {
      const float p0 = exp2f(s0[2 * t]), p1 = exp2f(s0[2 * t + 1]);
      const float r0 = exp2f(s1[2 * t]), r1 = exp2f(s1[2 * t + 1]);
      lsum += (p0 + p1) + (r0 + r1);
      w0[t] = pk2(p0, p1);
      w1[t] = pk2(r0, r1);
    }

    // half-exchange: A-frag k-slot needs keys kp*16 + hi*8 + 0..7; the missing
    // 8 keys live in lane^32. v_permlane32_swap: d.hi <-> s.lo gives both outputs.
    asm volatile("v_permlane32_swap_b32 %0, %1" : "+v"(w0[0]), "+v"(w0[2]));
    asm volatile("v_permlane32_swap_b32 %0, %1" : "+v"(w0[1]), "+v"(w0[3]));
    asm volatile("v_permlane32_swap_b32 %0, %1" : "+v"(w0[4]), "+v"(w0[6]));
    asm volatile("v_permlane32_swap_b32 %0, %1" : "+v"(w0[5]), "+v"(w0[7]));
    asm volatile("v_permlane32_swap_b32 %0, %1" : "+v"(w1[0]), "+v"(w1[2]));
    asm volatile("v_permlane32_swap_b32 %0, %1" : "+v"(w1[1]), "+v"(w1[3]));
    asm volatile("v_permlane32_swap_b32 %0, %1" : "+v"(w1[4]), "+v"(w1[6]));
    asm volatile("v_permlane32_swap_b32 %0, %1" : "+v"(w1[5]), "+v"(w1[7]));

    const bf16x8 pa0 = __builtin_bit_cast(bf16x8, (u32x4){w0[0], w0[1], w0[2], w0[3]});
    const bf16x8 pa1 = __builtin_bit_cast(bf16x8, (u32x4){w0[4], w0[5], w0[6], w0[7]});
    const bf16x8 pa2 = __builtin_bit_cast(bf16x8, (u32x4){w1[0], w1[1], w1[2], w1[3]});
    const bf16x8 pa3 = __builtin_bit_cast(bf16x8, (u32x4){w1[4], w1[5], w1[6], w1[7]});

    // PV: O[q][d] += P·V ; B = Vs[d][key] col=d, k=key
#pragma unroll
    for (int kp = 0; kp < 4; ++kp) {
      const bf16x8 paf = (kp == 0) ? pa0 : (kp == 1) ? pa1 : (kp == 2) ? pa2 : pa3;
      const bf16x8 vf0 = *(const bf16x8*)&Vs[(c)      * AP + kp * 16 + hi * 8];
      const bf16x8 vf1 = *(const bf16x8*)&Vs[(32 + c) * AP + kp * 16 + hi * 8];
      oacc0 = MFMA32(paf, vf0, oacc0);
      oacc1 = MFMA32(paf, vf1, oacc1);
    }
  }

  // column sum: lanes c and c+32 hold complementary key-rows of column q=c
  lsum += __shfl_xor(lsum, 32);

  // O /= l, write in place over this wave's own Q rows.
  // oacc reg j: q = qrow + (j&3)+8*(j>>2)+4*hi, d = dblk*32 + c.
#pragma unroll
  for (int j = 0; j < 16; ++j) {
    const int qloc = (j & 3) + 8 * (j >> 2) + 4 * hi;
    const float li = fmaxf(__shfl(lsum, qloc), 1e-30f);
    const int q = qrow + qloc;
    Q[(size_t)q * 64 + c]      = (bf16_t)(oacc0[j] / li);
    Q[(size_t)q * 64 + 32 + c] = (bf16_t)(oacc1[j] / li);
  }
}

// ---------------- launch ----------------------------------------------------------
extern "C" void kernel_launch(void* const* d_in, const int* in_sizes, int n_in,
                              void* d_out, int out_size, void* d_ws, size_t ws_size,
                              hipStream_t stream) {
  const void* x      = d_in[0];   // (2,2048,1024)
  const void* W_attn = d_in[1];   // (1024,3072)
  const void* b_attn = d_in[2];   // (3072,)
  const void* W_proj = d_in[3];   // (1024,1024)
  const void* b_proj = d_in[4];   // (1024,)

  char* ws = (char*)d_ws;
  size_t off = 0;
  auto alloc = [&](size_t bytes) {
    char* p = ws + off;
    off += (bytes + 255) & ~(size_t)255;
    return p;
  };
  int*    flag = (int*)alloc(256);
  bf16_t* Qs   = (bf16_t*)alloc((size_t)32 * 2048 * 64 * 2);   // Q, then O in place
  bf16_t* Kb   = (bf16_t*)alloc((size_t)32 * 2048 * 64 * 2);
  bf16_t* Wat  = (bf16_t*)alloc((size_t)3072 * 1024 * 2);      // W_attn^T (N,K) bf16
  bf16_t* Wpt  = (bf16_t*)alloc((size_t)1024 * 1024 * 2);      // W_proj^T bf16
  bf16_t* dout_bf = (bf16_t*)d_out;

  detect_dtype<<<1, 256, 0, stream>>>((const unsigned short*)x, flag);

  cvt_x<<<2048, 256, 0, stream>>>((const float*)x, dout_bf, flag);

  transpose_any<<<dim3(3072 / 32, 1024 / 32), dim3(32, 8), 0, stream>>>(W_attn, Wat, 1024, 3072, flag);
  transpose_any<<<dim3(1024 / 32, 1024 / 32), dim3(32, 8), 0, stream>>>(W_proj, Wpt, 1024, 1024, flag);

  gemm_bt<1><<<dim3(3072 / 128, 4096 / 128), 256, 0, stream>>>(
      x, dout_bf, Wat, b_attn, nullptr, Qs, Kb, dout_bf, 4096, 3072, 1024, flag);

  attn_kernel<<<dim3(1024), 128, 0, stream>>>(Qs, Kb, dout_bf, flag);

  gemm_bt<2><<<dim3(1024 / 128, 4096 / 128), 256, 0, stream>>>(
      Qs, nullptr, Wpt, b_proj, d_out, nullptr, nullptr, dout_bf, 4096, 1024, 1024, flag);
}